// Round 1
// baseline (1832.522 us; speedup 1.0000x reference)
//
#include <hip/hip_runtime.h>
#include <cstdint>
#include <cstddef>

#define B_ 8
#define C_ 2048
#define F_ 512
#define TTILES 32            // C_/64
#define NPAIRS 528           // TTILES*(TTILES+1)/2 upper-triangular 64x64 tile pairs

// ---------------------------------------------------------------------------
// ws layout (bytes):
//   nrm   double[B*C]            @ 0          131072
//   bits  uint32[B*C*64]         @ 131072     4194304   (row-major bitmask of A)
//   deg   uint32[B*C]            @ 4325376    65536
//   sinv  float[B*C]             @ 4390912    65536
//   lx    float[B*C*F]           @ 4456448    33554432
// total ~38.0 MB
// ---------------------------------------------------------------------------

__global__ __launch_bounds__(256) void kzero(uint32_t* __restrict__ p) {
  p[blockIdx.x * 256 + threadIdx.x] = 0u;
}

// ---- row norms, fp64 accumulate (exact squares of fp32 values) ----
__global__ __launch_bounds__(256) void knorm(const float* __restrict__ x,
                                             double* __restrict__ nrm) {
  int row = blockIdx.x * 4 + (threadIdx.x >> 6);
  int lane = threadIdx.x & 63;
  const float4* xr = reinterpret_cast<const float4*>(x + (size_t)row * F_);
  float4 v1 = xr[lane];
  float4 v2 = xr[lane + 64];
  double s = (double)v1.x * v1.x + (double)v1.y * v1.y +
             (double)v1.z * v1.z + (double)v1.w * v1.w +
             (double)v2.x * v2.x + (double)v2.y * v2.y +
             (double)v2.z * v2.z + (double)v2.w * v2.w;
#pragma unroll
  for (int off = 32; off > 0; off >>= 1) s += __shfl_down(s, off, 64);
  if (lane == 0) nrm[row] = sqrt(s);
}

// ---- fp64 Gram + binarize + bitmask + degree (upper-triangle tiles, mirrored) ----
__global__ __launch_bounds__(256) void kgram(const float* __restrict__ x,
                                             const double* __restrict__ nrm,
                                             uint32_t* __restrict__ bits,
                                             uint32_t* __restrict__ deg) {
  int b = blockIdx.y;
  // linear tile id -> (I,J), I<=J
  int t = (int)blockIdx.x, I = 0;
  while (t >= TTILES - I) { t -= TTILES - I; ++I; }
  int J = I + t;
  bool offdiag = (I != J);
  int c0 = I * 64, d0 = J * 64;
  int tid = threadIdx.x, tx = tid & 15, ty = tid >> 4;

  __shared__ __align__(16) double As[16][66];   // [k][row], padded
  __shared__ __align__(16) double Bs[16][66];
  __shared__ uint32_t lb[64][2];
  __shared__ uint32_t lbT[64][2];

  double acc[4][4];
#pragma unroll
  for (int i = 0; i < 4; ++i)
#pragma unroll
    for (int j = 0; j < 4; ++j) acc[i][j] = 0.0;

  const float* xb = x + (size_t)b * C_ * F_;

  for (int kc = 0; kc < F_ / 16; ++kc) {
    int k0 = kc * 16;
#pragma unroll
    for (int p = 0; p < 4; ++p) {
      int r = (tid >> 4) + p * 16;
      int k = tid & 15;
      As[k][r] = (double)xb[(size_t)(c0 + r) * F_ + k0 + k];
      Bs[k][r] = (double)xb[(size_t)(d0 + r) * F_ + k0 + k];
    }
    __syncthreads();
#pragma unroll
    for (int kk = 0; kk < 16; ++kk) {
      double a[4], bv[4];
#pragma unroll
      for (int i = 0; i < 4; ++i) a[i] = As[kk][ty * 4 + i];
#pragma unroll
      for (int j = 0; j < 4; ++j) bv[j] = Bs[kk][tx * 4 + j];
#pragma unroll
      for (int i = 0; i < 4; ++i)
#pragma unroll
        for (int j = 0; j < 4; ++j) acc[i][j] = fma(a[i], bv[j], acc[i][j]);
    }
    __syncthreads();
  }

  if (tid < 64) { lb[tid][0] = 0; lb[tid][1] = 0; lbT[tid][0] = 0; lbT[tid][1] = 0; }
  __syncthreads();

  double nc[4], nd[4];
#pragma unroll
  for (int i = 0; i < 4; ++i) nc[i] = nrm[b * C_ + c0 + ty * 4 + i];
#pragma unroll
  for (int j = 0; j < 4; ++j) nd[j] = nrm[b * C_ + d0 + tx * 4 + j];

#pragma unroll
  for (int i = 0; i < 4; ++i) {
#pragma unroll
    for (int j = 0; j < 4; ++j) {
      // corr > 0.005  <=>  num > 0.005*nc*nd  (denom > 0)
      if (acc[i][j] > 0.005 * (nc[i] * nd[j])) {
        int colb = tx * 4 + j;
        int rowb = ty * 4 + i;
        atomicOr(&lb[rowb][colb >> 5], 1u << (colb & 31));
        if (offdiag) atomicOr(&lbT[colb][rowb >> 5], 1u << (rowb & 31));
      }
    }
  }
  __syncthreads();

  if (tid < 64) {
    uint32_t w0 = lb[tid][0], w1 = lb[tid][1];
    size_t base = ((size_t)b * C_ + c0 + tid) * 64 + (size_t)J * 2;
    bits[base] = w0; bits[base + 1] = w1;
    atomicAdd(&deg[b * C_ + c0 + tid], (uint32_t)(__popc(w0) + __popc(w1)));
  } else if (offdiag && tid < 128) {
    int r = tid - 64;
    uint32_t w0 = lbT[r][0], w1 = lbT[r][1];
    size_t base = ((size_t)b * C_ + d0 + r) * 64 + (size_t)I * 2;
    bits[base] = w0; bits[base + 1] = w1;
    atomicAdd(&deg[b * C_ + d0 + r], (uint32_t)(__popc(w0) + __popc(w1)));
  }
}

// ---- sinv = 1/sqrt(deg) ----
__global__ __launch_bounds__(256) void ksinv(const uint32_t* __restrict__ deg,
                                             float* __restrict__ sinv) {
  int i = blockIdx.x * 256 + threadIdx.x;
  sinv[i] = 1.0f / sqrtf((float)deg[i]);
}

// ---- propagation: lx[c,f] = s_c * sum_{d: A[c,d]} s_d * h[d,f]  (fp32 vector) ----
__global__ __launch_bounds__(256) void kprop(const float* __restrict__ h,
                                             const float* __restrict__ sinv,
                                             const uint32_t* __restrict__ bits,
                                             float* __restrict__ lx) {
  int b = blockIdx.z;
  int c0 = blockIdx.x * 64, f0 = blockIdx.y * 64;
  int tid = threadIdx.x, tx = tid & 15, ty = tid >> 4;
  __shared__ __align__(16) float Hs[64][68];
  float4 acc[4];
#pragma unroll
  for (int i = 0; i < 4; ++i) acc[i] = make_float4(0.f, 0.f, 0.f, 0.f);

  const float* hb = h + (size_t)b * C_ * F_;
  const float* sv = sinv + b * C_;

  for (int Jc = 0; Jc < C_ / 64; ++Jc) {
    int d0 = Jc * 64;
#pragma unroll
    for (int p = 0; p < 4; ++p) {
      int r = (tid >> 4) + p * 16;
      float s = sv[d0 + r];
      float4 v = *reinterpret_cast<const float4*>(&hb[(size_t)(d0 + r) * F_ + f0 + tx * 4]);
      v.x *= s; v.y *= s; v.z *= s; v.w *= s;
      *reinterpret_cast<float4*>(&Hs[r][tx * 4]) = v;
    }
    __syncthreads();

    uint32_t wlo[4], whi[4];
#pragma unroll
    for (int i = 0; i < 4; ++i) {
      const uint32_t* rw = bits + ((size_t)b * C_ + c0 + ty * 4 + i) * 64 + Jc * 2;
      wlo[i] = rw[0]; whi[i] = rw[1];
    }
#pragma unroll 8
    for (int d = 0; d < 32; ++d) {
      float4 v = *reinterpret_cast<const float4*>(&Hs[d][tx * 4]);
#pragma unroll
      for (int i = 0; i < 4; ++i) {
        float m = (float)(wlo[i] & 1u); wlo[i] >>= 1;
        acc[i].x = fmaf(v.x, m, acc[i].x);
        acc[i].y = fmaf(v.y, m, acc[i].y);
        acc[i].z = fmaf(v.z, m, acc[i].z);
        acc[i].w = fmaf(v.w, m, acc[i].w);
      }
    }
#pragma unroll 8
    for (int d = 0; d < 32; ++d) {
      float4 v = *reinterpret_cast<const float4*>(&Hs[32 + d][tx * 4]);
#pragma unroll
      for (int i = 0; i < 4; ++i) {
        float m = (float)(whi[i] & 1u); whi[i] >>= 1;
        acc[i].x = fmaf(v.x, m, acc[i].x);
        acc[i].y = fmaf(v.y, m, acc[i].y);
        acc[i].z = fmaf(v.z, m, acc[i].z);
        acc[i].w = fmaf(v.w, m, acc[i].w);
      }
    }
    __syncthreads();
  }

#pragma unroll
  for (int i = 0; i < 4; ++i) {
    float s = sv[c0 + ty * 4 + i];
    float4 o = make_float4(acc[i].x * s, acc[i].y * s, acc[i].z * s, acc[i].w * s);
    *reinterpret_cast<float4*>(&lx[((size_t)b * C_ + c0 + ty * 4 + i) * F_ + f0 + tx * 4]) = o;
  }
}

// ---- dense GEMM: out = relu(lx @ W + bias)   M=B*C, K=F, N=F ----
__global__ __launch_bounds__(256) void kgemm(const float* __restrict__ A,
                                             const float* __restrict__ W,
                                             const float* __restrict__ bias,
                                             float* __restrict__ out) {
  int m0 = blockIdx.x * 64, n0 = blockIdx.y * 64;
  int tid = threadIdx.x, tx = tid & 15, ty = tid >> 4;
  __shared__ __align__(16) float As[16][68];   // [k][m]
  __shared__ __align__(16) float Bs[16][68];   // [k][n]
  float acc[4][4];
#pragma unroll
  for (int i = 0; i < 4; ++i)
#pragma unroll
    for (int j = 0; j < 4; ++j) acc[i][j] = 0.f;

  for (int kc = 0; kc < F_ / 16; ++kc) {
    int k0 = kc * 16;
#pragma unroll
    for (int p = 0; p < 4; ++p) {
      int r = (tid >> 4) + p * 16;
      int k = tid & 15;
      As[k][r] = A[(size_t)(m0 + r) * F_ + k0 + k];
    }
    {
      int k = tid >> 4;
      int col = (tid & 15) * 4;
      float4 v = *reinterpret_cast<const float4*>(&W[(size_t)(k0 + k) * F_ + n0 + col]);
      *reinterpret_cast<float4*>(&Bs[k][col]) = v;
    }
    __syncthreads();
#pragma unroll
    for (int kk = 0; kk < 16; ++kk) {
      float4 a = *reinterpret_cast<const float4*>(&As[kk][ty * 4]);
      float4 bv = *reinterpret_cast<const float4*>(&Bs[kk][tx * 4]);
      acc[0][0] = fmaf(a.x, bv.x, acc[0][0]); acc[0][1] = fmaf(a.x, bv.y, acc[0][1]);
      acc[0][2] = fmaf(a.x, bv.z, acc[0][2]); acc[0][3] = fmaf(a.x, bv.w, acc[0][3]);
      acc[1][0] = fmaf(a.y, bv.x, acc[1][0]); acc[1][1] = fmaf(a.y, bv.y, acc[1][1]);
      acc[1][2] = fmaf(a.y, bv.z, acc[1][2]); acc[1][3] = fmaf(a.y, bv.w, acc[1][3]);
      acc[2][0] = fmaf(a.z, bv.x, acc[2][0]); acc[2][1] = fmaf(a.z, bv.y, acc[2][1]);
      acc[2][2] = fmaf(a.z, bv.z, acc[2][2]); acc[2][3] = fmaf(a.z, bv.w, acc[2][3]);
      acc[3][0] = fmaf(a.w, bv.x, acc[3][0]); acc[3][1] = fmaf(a.w, bv.y, acc[3][1]);
      acc[3][2] = fmaf(a.w, bv.z, acc[3][2]); acc[3][3] = fmaf(a.w, bv.w, acc[3][3]);
    }
    __syncthreads();
  }
  float bv = bias[0];
#pragma unroll
  for (int i = 0; i < 4; ++i) {
    float4 o = make_float4(fmaxf(acc[i][0] + bv, 0.f), fmaxf(acc[i][1] + bv, 0.f),
                           fmaxf(acc[i][2] + bv, 0.f), fmaxf(acc[i][3] + bv, 0.f));
    *reinterpret_cast<float4*>(&out[(size_t)(m0 + ty * 4 + i) * F_ + n0 + tx * 4]) = o;
  }
}

extern "C" void kernel_launch(void* const* d_in, const int* in_sizes, int n_in,
                              void* d_out, int out_size, void* d_ws, size_t ws_size,
                              hipStream_t stream) {
  (void)in_sizes; (void)n_in; (void)out_size; (void)ws_size;
  const float* x  = (const float*)d_in[0];
  const float* W1 = (const float*)d_in[1];
  const float* b1 = (const float*)d_in[2];
  const float* W2 = (const float*)d_in[3];
  const float* b2 = (const float*)d_in[4];
  float* out = (float*)d_out;

  char* ws = (char*)d_ws;
  double*   nrm  = (double*)(ws);
  uint32_t* bits = (uint32_t*)(ws + 131072);
  uint32_t* deg  = (uint32_t*)(ws + 131072 + 4194304);
  float*    sinv = (float*)(ws + 131072 + 4194304 + 65536);
  float*    lx   = (float*)(ws + 131072 + 4194304 + 131072);

  // zero degrees (ws is poisoned 0xAA before every launch)
  kzero<<<dim3(B_ * C_ / 256), 256, 0, stream>>>(deg);
  knorm<<<dim3(B_ * C_ / 4), 256, 0, stream>>>(x, nrm);
  kgram<<<dim3(NPAIRS, B_), 256, 0, stream>>>(x, nrm, bits, deg);
  ksinv<<<dim3(B_ * C_ / 256), 256, 0, stream>>>(deg, sinv);

  // layer 1: h = x
  kprop<<<dim3(TTILES, F_ / 64, B_), 256, 0, stream>>>(x, sinv, bits, lx);
  kgemm<<<dim3(B_ * C_ / 64, F_ / 64), 256, 0, stream>>>(lx, W1, b1, out);
  // layer 2: h = out (h1 lives in d_out, then overwritten by final result)
  kprop<<<dim3(TTILES, F_ / 64, B_), 256, 0, stream>>>(out, sinv, bits, lx);
  kgemm<<<dim3(B_ * C_ / 64, F_ / 64), 256, 0, stream>>>(lx, W2, b2, out);
}

// Round 3
// 1024.779 us; speedup vs baseline: 1.7882x; 1.7882x over previous
//
#include <hip/hip_runtime.h>
#include <hip/hip_bf16.h>
#include <cstdint>
#include <cstddef>

#define B_ 8
#define C_ 2048
#define F_ 512
#define TTILES 32            // C_/64
#define NPAIRS 528           // TTILES*(TTILES+1)/2

typedef short bf16x8 __attribute__((ext_vector_type(8)));
typedef float f32x4 __attribute__((ext_vector_type(4)));

// ---------------------------------------------------------------------------
// ws layout (bytes):
//   nrm   double[B*C]            @ 0          131072
//   bits  uint32[B*C*64]         @ 131072     4194304
//   deg   uint32[B*C]            @ 4325376    65536
//   sinv  float[B*C]             @ 4390912    65536
//   g     float[B*C*F]           @ 4456448    33554432   (h @ W buffer)
// ---------------------------------------------------------------------------

__global__ __launch_bounds__(256) void kzero(uint32_t* __restrict__ p) {
  p[blockIdx.x * 256 + threadIdx.x] = 0u;
}

__global__ __launch_bounds__(256) void knorm(const float* __restrict__ x,
                                             double* __restrict__ nrm) {
  int row = blockIdx.x * 4 + (threadIdx.x >> 6);
  int lane = threadIdx.x & 63;
  const float4* xr = reinterpret_cast<const float4*>(x + (size_t)row * F_);
  float4 v1 = xr[lane];
  float4 v2 = xr[lane + 64];
  double s = (double)v1.x * v1.x + (double)v1.y * v1.y +
             (double)v1.z * v1.z + (double)v1.w * v1.w +
             (double)v2.x * v2.x + (double)v2.y * v2.y +
             (double)v2.z * v2.z + (double)v2.w * v2.w;
#pragma unroll
  for (int off = 32; off > 0; off >>= 1) s += __shfl_down(s, off, 64);
  if (lane == 0) nrm[row] = sqrt(s);
}

// ---- fp64 Gram + binarize + bitmask + degree (unchanged, correctness anchor) ----
__global__ __launch_bounds__(256) void kgram(const float* __restrict__ x,
                                             const double* __restrict__ nrm,
                                             uint32_t* __restrict__ bits,
                                             uint32_t* __restrict__ deg) {
  int b = blockIdx.y;
  int t = (int)blockIdx.x, I = 0;
  while (t >= TTILES - I) { t -= TTILES - I; ++I; }
  int J = I + t;
  bool offdiag = (I != J);
  int c0 = I * 64, d0 = J * 64;
  int tid = threadIdx.x, tx = tid & 15, ty = tid >> 4;

  __shared__ __align__(16) double As[16][66];
  __shared__ __align__(16) double Bs[16][66];
  __shared__ uint32_t lb[64][2];
  __shared__ uint32_t lbT[64][2];

  double acc[4][4];
#pragma unroll
  for (int i = 0; i < 4; ++i)
#pragma unroll
    for (int j = 0; j < 4; ++j) acc[i][j] = 0.0;

  const float* xb = x + (size_t)b * C_ * F_;

  for (int kc = 0; kc < F_ / 16; ++kc) {
    int k0 = kc * 16;
#pragma unroll
    for (int p = 0; p < 4; ++p) {
      int r = (tid >> 4) + p * 16;
      int k = tid & 15;
      As[k][r] = (double)xb[(size_t)(c0 + r) * F_ + k0 + k];
      Bs[k][r] = (double)xb[(size_t)(d0 + r) * F_ + k0 + k];
    }
    __syncthreads();
#pragma unroll
    for (int kk = 0; kk < 16; ++kk) {
      double a[4], bv[4];
#pragma unroll
      for (int i = 0; i < 4; ++i) a[i] = As[kk][ty * 4 + i];
#pragma unroll
      for (int j = 0; j < 4; ++j) bv[j] = Bs[kk][tx * 4 + j];
#pragma unroll
      for (int i = 0; i < 4; ++i)
#pragma unroll
        for (int j = 0; j < 4; ++j) acc[i][j] = fma(a[i], bv[j], acc[i][j]);
    }
    __syncthreads();
  }

  if (tid < 64) { lb[tid][0] = 0; lb[tid][1] = 0; lbT[tid][0] = 0; lbT[tid][1] = 0; }
  __syncthreads();

  double nc[4], nd[4];
#pragma unroll
  for (int i = 0; i < 4; ++i) nc[i] = nrm[b * C_ + c0 + ty * 4 + i];
#pragma unroll
  for (int j = 0; j < 4; ++j) nd[j] = nrm[b * C_ + d0 + tx * 4 + j];

#pragma unroll
  for (int i = 0; i < 4; ++i) {
#pragma unroll
    for (int j = 0; j < 4; ++j) {
      if (acc[i][j] > 0.005 * (nc[i] * nd[j])) {
        int colb = tx * 4 + j;
        int rowb = ty * 4 + i;
        atomicOr(&lb[rowb][colb >> 5], 1u << (colb & 31));
        if (offdiag) atomicOr(&lbT[colb][rowb >> 5], 1u << (rowb & 31));
      }
    }
  }
  __syncthreads();

  if (tid < 64) {
    uint32_t w0 = lb[tid][0], w1 = lb[tid][1];
    size_t base = ((size_t)b * C_ + c0 + tid) * 64 + (size_t)J * 2;
    bits[base] = w0; bits[base + 1] = w1;
    atomicAdd(&deg[b * C_ + c0 + tid], (uint32_t)(__popc(w0) + __popc(w1)));
  } else if (offdiag && tid < 128) {
    int r = tid - 64;
    uint32_t w0 = lbT[r][0], w1 = lbT[r][1];
    size_t base = ((size_t)b * C_ + d0 + r) * 64 + (size_t)I * 2;
    bits[base] = w0; bits[base + 1] = w1;
    atomicAdd(&deg[b * C_ + d0 + r], (uint32_t)(__popc(w0) + __popc(w1)));
  }
}

__global__ __launch_bounds__(256) void ksinv(const uint32_t* __restrict__ deg,
                                             float* __restrict__ sinv) {
  int i = blockIdx.x * 256 + threadIdx.x;
  sinv[i] = 1.0f / sqrtf((float)deg[i]);
}

// ---- dense GEMM (fp32): g = A @ W   (no bias/relu; they fuse into kprop) ----
__global__ __launch_bounds__(256) void kgemm_plain(const float* __restrict__ A,
                                                   const float* __restrict__ W,
                                                   float* __restrict__ out) {
  int m0 = blockIdx.x * 64, n0 = blockIdx.y * 64;
  int tid = threadIdx.x, tx = tid & 15, ty = tid >> 4;
  __shared__ __align__(16) float As[16][68];
  __shared__ __align__(16) float Bs[16][68];
  float acc[4][4];
#pragma unroll
  for (int i = 0; i < 4; ++i)
#pragma unroll
    for (int j = 0; j < 4; ++j) acc[i][j] = 0.f;

  for (int kc = 0; kc < F_ / 16; ++kc) {
    int k0 = kc * 16;
#pragma unroll
    for (int p = 0; p < 4; ++p) {
      int r = (tid >> 4) + p * 16;
      int k = tid & 15;
      As[k][r] = A[(size_t)(m0 + r) * F_ + k0 + k];
    }
    {
      int k = tid >> 4;
      int col = (tid & 15) * 4;
      float4 v = *reinterpret_cast<const float4*>(&W[(size_t)(k0 + k) * F_ + n0 + col]);
      *reinterpret_cast<float4*>(&Bs[k][col]) = v;
    }
    __syncthreads();
#pragma unroll
    for (int kk = 0; kk < 16; ++kk) {
      float4 a = *reinterpret_cast<const float4*>(&As[kk][ty * 4]);
      float4 bv = *reinterpret_cast<const float4*>(&Bs[kk][tx * 4]);
      acc[0][0] = fmaf(a.x, bv.x, acc[0][0]); acc[0][1] = fmaf(a.x, bv.y, acc[0][1]);
      acc[0][2] = fmaf(a.x, bv.z, acc[0][2]); acc[0][3] = fmaf(a.x, bv.w, acc[0][3]);
      acc[1][0] = fmaf(a.y, bv.x, acc[1][0]); acc[1][1] = fmaf(a.y, bv.y, acc[1][1]);
      acc[1][2] = fmaf(a.y, bv.z, acc[1][2]); acc[1][3] = fmaf(a.y, bv.w, acc[1][3]);
      acc[2][0] = fmaf(a.z, bv.x, acc[2][0]); acc[2][1] = fmaf(a.z, bv.y, acc[2][1]);
      acc[2][2] = fmaf(a.z, bv.z, acc[2][2]); acc[2][3] = fmaf(a.z, bv.w, acc[2][3]);
      acc[3][0] = fmaf(a.w, bv.x, acc[3][0]); acc[3][1] = fmaf(a.w, bv.y, acc[3][1]);
      acc[3][2] = fmaf(a.w, bv.z, acc[3][2]); acc[3][3] = fmaf(a.w, bv.w, acc[3][3]);
    }
    __syncthreads();
  }
#pragma unroll
  for (int i = 0; i < 4; ++i) {
    float4 o = make_float4(acc[i][0], acc[i][1], acc[i][2], acc[i][3]);
    *reinterpret_cast<float4*>(&out[(size_t)(m0 + ty * 4 + i) * F_ + n0 + tx * 4]) = o;
  }
}

// ---- MFMA propagation: out = relu(s_c * sum_d mask[c,d]*(s_d*g[d,f]) + bias) ----
// A-operand = exact 0/1 bf16 from bitmask; B-operand = hi/lo bf16 split of s_d*g.
__global__ __launch_bounds__(256) void kprop_fused(const float* __restrict__ g,
                                                   const float* __restrict__ sinv,
                                                   const uint32_t* __restrict__ bits,
                                                   const float* __restrict__ bias,
                                                   float* __restrict__ out) {
  int b = blockIdx.z;
  int c0 = blockIdx.x * 64, f0 = blockIdx.y * 64;
  int tid = threadIdx.x;
  int l = tid & 63, w = tid >> 6;
  int wc = w >> 1, wf = w & 1;          // wave -> 32x32 (c,f) sub-tile
  int lg = l >> 4, li = l & 15;

  __shared__ ushort vhi[64][72];        // v^T tile: [f][d], stride 72 (bank-balanced)
  __shared__ ushort vlo[64][72];
  __shared__ uint32_t blds[64][68];     // this c-tile's 64 bit-rows (full K)

  // prefetch bits: 64 rows x 64 words, contiguous 16 KB, coalesced uint4
  const uint32_t* bp = bits + (((size_t)b * C_ + c0) << 6);
#pragma unroll
  for (int t = 0; t < 4; ++t) {
    int gi = (t * 256 + tid) * 4;
    uint4 q = *reinterpret_cast<const uint4*>(bp + gi);
    int row = gi >> 6, col = gi & 63;
    *reinterpret_cast<uint4*>(&blds[row][col]) = q;
  }

  f32x4 acc[2][2];
#pragma unroll
  for (int m = 0; m < 2; ++m)
#pragma unroll
    for (int n = 0; n < 2; ++n) acc[m][n] = (f32x4){0.f, 0.f, 0.f, 0.f};

  const float* gb = g + (size_t)b * C_ * F_;
  const float* sv = sinv + b * C_;
  int r = tid >> 4;      // 0..15: d-pair index within 32-row half
  int fq = tid & 15;

  for (int d0 = 0; d0 < C_; d0 += 64) {
    __syncthreads();     // previous iter's reads done before overwrite (covers prefetch too)
#pragma unroll
    for (int p = 0; p < 2; ++p) {
      int dl = p * 32 + 2 * r;
      float s0 = sv[d0 + dl], s1 = sv[d0 + dl + 1];
      const float* g0 = &gb[(size_t)(d0 + dl) * F_ + f0];
      const float* g1 = g0 + F_;
#pragma unroll
      for (int j = 0; j < 4; ++j) {
        int fp = fq + 16 * j;          // f-assignment spreads banks
        float v0 = s0 * g0[fp];
        float v1 = s1 * g1[fp];
        __hip_bfloat16 h0 = __float2bfloat16(v0);
        __hip_bfloat16 h1 = __float2bfloat16(v1);
        __hip_bfloat16 e0 = __float2bfloat16(v0 - __bfloat162float(h0));
        __hip_bfloat16 e1 = __float2bfloat16(v1 - __bfloat162float(h1));
        uint32_t ph = (uint32_t)__builtin_bit_cast(unsigned short, h0) |
                      ((uint32_t)__builtin_bit_cast(unsigned short, h1) << 16);
        uint32_t pl = (uint32_t)__builtin_bit_cast(unsigned short, e0) |
                      ((uint32_t)__builtin_bit_cast(unsigned short, e1) << 16);
        *reinterpret_cast<uint32_t*>(&vhi[fp][dl]) = ph;
        *reinterpret_cast<uint32_t*>(&vlo[fp][dl]) = pl;
      }
    }
    __syncthreads();

    int wbase = d0 >> 5;
#pragma unroll
    for (int kk = 0; kk < 2; ++kk) {
      uint32_t wd0 = blds[wc * 32 + li][wbase + kk];
      uint32_t wd1 = blds[wc * 32 + 16 + li][wbase + kk];
      uint32_t by0 = (wd0 >> (lg * 8)) & 0xFFu;
      uint32_t by1 = (wd1 >> (lg * 8)) & 0xFFu;
      bf16x8 a0, a1;
#pragma unroll
      for (int j = 0; j < 8; ++j) {
        a0[j] = (short)(((by0 >> j) & 1u) ? 0x3F80 : 0);
        a1[j] = (short)(((by1 >> j) & 1u) ? 0x3F80 : 0);
      }
      int dk = kk * 32 + lg * 8;
      bf16x8 bh0 = *reinterpret_cast<const bf16x8*>(&vhi[wf * 32 + li][dk]);
      bf16x8 bl0 = *reinterpret_cast<const bf16x8*>(&vlo[wf * 32 + li][dk]);
      bf16x8 bh1 = *reinterpret_cast<const bf16x8*>(&vhi[wf * 32 + 16 + li][dk]);
      bf16x8 bl1 = *reinterpret_cast<const bf16x8*>(&vlo[wf * 32 + 16 + li][dk]);
      acc[0][0] = __builtin_amdgcn_mfma_f32_16x16x32_bf16(a0, bh0, acc[0][0], 0, 0, 0);
      acc[0][0] = __builtin_amdgcn_mfma_f32_16x16x32_bf16(a0, bl0, acc[0][0], 0, 0, 0);
      acc[0][1] = __builtin_amdgcn_mfma_f32_16x16x32_bf16(a0, bh1, acc[0][1], 0, 0, 0);
      acc[0][1] = __builtin_amdgcn_mfma_f32_16x16x32_bf16(a0, bl1, acc[0][1], 0, 0, 0);
      acc[1][0] = __builtin_amdgcn_mfma_f32_16x16x32_bf16(a1, bh0, acc[1][0], 0, 0, 0);
      acc[1][0] = __builtin_amdgcn_mfma_f32_16x16x32_bf16(a1, bl0, acc[1][0], 0, 0, 0);
      acc[1][1] = __builtin_amdgcn_mfma_f32_16x16x32_bf16(a1, bh1, acc[1][1], 0, 0, 0);
      acc[1][1] = __builtin_amdgcn_mfma_f32_16x16x32_bf16(a1, bl1, acc[1][1], 0, 0, 0);
    }
  }

  // epilogue: relu(s_c * acc + bias); C/D layout: col=lane&15, row=(lane>>4)*4+q
  float bb = bias[0];
#pragma unroll
  for (int m = 0; m < 2; ++m) {
    int rowb = c0 + wc * 32 + m * 16 + lg * 4;
    f32x4 sc = *reinterpret_cast<const f32x4*>(&sv[rowb]);
#pragma unroll
    for (int n = 0; n < 2; ++n) {
      int col = f0 + wf * 32 + n * 16 + li;
#pragma unroll
      for (int q = 0; q < 4; ++q) {
        float o = sc[q] * acc[m][n][q] + bb;
        out[(size_t)(b * C_ + rowb + q) * F_ + col] = fmaxf(o, 0.f);
      }
    }
  }
}

extern "C" void kernel_launch(void* const* d_in, const int* in_sizes, int n_in,
                              void* d_out, int out_size, void* d_ws, size_t ws_size,
                              hipStream_t stream) {
  (void)in_sizes; (void)n_in; (void)out_size; (void)ws_size;
  const float* x  = (const float*)d_in[0];
  const float* W1 = (const float*)d_in[1];
  const float* b1 = (const float*)d_in[2];
  const float* W2 = (const float*)d_in[3];
  const float* b2 = (const float*)d_in[4];
  float* out = (float*)d_out;

  char* ws = (char*)d_ws;
  double*   nrm  = (double*)(ws);
  uint32_t* bits = (uint32_t*)(ws + 131072);
  uint32_t* deg  = (uint32_t*)(ws + 131072 + 4194304);
  float*    sinv = (float*)(ws + 131072 + 4194304 + 65536);
  float*    g    = (float*)(ws + 131072 + 4194304 + 131072);

  kzero<<<dim3(B_ * C_ / 256), 256, 0, stream>>>(deg);
  knorm<<<dim3(B_ * C_ / 4), 256, 0, stream>>>(x, nrm);
  kgram<<<dim3(NPAIRS, B_), 256, 0, stream>>>(x, nrm, bits, deg);
  ksinv<<<dim3(B_ * C_ / 256), 256, 0, stream>>>(deg, sinv);

  // layer 1: g = x @ W1 ; h1 = relu(L @ g + b1)  -> d_out
  kgemm_plain<<<dim3(B_ * C_ / 64, F_ / 64), 256, 0, stream>>>(x, W1, g);
  kprop_fused<<<dim3(TTILES, F_ / 64, B_), 256, 0, stream>>>(g, sinv, bits, b1, out);
  // layer 2: g = h1 @ W2 ; out = relu(L @ g + b2) -> d_out
  kgemm_plain<<<dim3(B_ * C_ / 64, F_ / 64), 256, 0, stream>>>(out, W2, g);
  kprop_fused<<<dim3(TTILES, F_ / 64, B_), 256, 0, stream>>>(g, sinv, bits, b2, out);
}

// Round 5
// 758.079 us; speedup vs baseline: 2.4173x; 1.3518x over previous
//
#include <hip/hip_runtime.h>
#include <hip/hip_bf16.h>
#include <cstdint>
#include <cstddef>

#define B_ 8
#define C_ 2048
#define F_ 512
#define TTILES 32            // C_/64
#define NPAIRS 528           // TTILES*(TTILES+1)/2
#define BAND 0.015f
#define FLAGCAP (1u << 20)

typedef short bf16x8 __attribute__((ext_vector_type(8)));
typedef float f32x4 __attribute__((ext_vector_type(4)));

// ---------------------------------------------------------------------------
// ws layout (bytes):
//   nrm   double[B*C]        @ 0          131072
//   bits  uint32[B*C*64]     @ 131072     4194304
//   sinv  float[B*C]         @ 4325376    65536
//   flagn uint32             @ 4390912    256
//   flags uint32[1M]         @ 4391168    4194304
//   xhi   ushort[B*C*F]      @ 8585472    16777216   } dead after kgram2;
//   xlo   ushort[B*C*F]      @ 25362688   16777216   } g (fp32, 33.5MB) overlays
//   g     float[B*C*F]       @ 8585472    (union with xhi+xlo)
// total ~40.2 MB
// ---------------------------------------------------------------------------

__global__ __launch_bounds__(64) void kzero1(uint32_t* __restrict__ flagn) {
  if (threadIdx.x == 0) *flagn = 0u;
}

// ---- split x into bf16 hi + lo (v = hi + lo, rel err ~2^-18) ----
__global__ __launch_bounds__(256) void ksplit(const float* __restrict__ x,
                                              ushort* __restrict__ xhi,
                                              ushort* __restrict__ xlo) {
  size_t i = ((size_t)blockIdx.x * 256 + threadIdx.x) * 8;
  float4 v0 = *reinterpret_cast<const float4*>(x + i);
  float4 v1 = *reinterpret_cast<const float4*>(x + i + 4);
  float vv[8] = {v0.x, v0.y, v0.z, v0.w, v1.x, v1.y, v1.z, v1.w};
  ushort h[8], lo[8];
#pragma unroll
  for (int j = 0; j < 8; ++j) {
    __hip_bfloat16 hh = __float2bfloat16(vv[j]);
    float r = vv[j] - __bfloat162float(hh);
    __hip_bfloat16 ll = __float2bfloat16(r);
    h[j]  = __builtin_bit_cast(unsigned short, hh);
    lo[j] = __builtin_bit_cast(unsigned short, ll);
  }
  *reinterpret_cast<uint4*>(xhi + i) = *reinterpret_cast<uint4*>(h);
  *reinterpret_cast<uint4*>(xlo + i) = *reinterpret_cast<uint4*>(lo);
}

__global__ __launch_bounds__(256) void knorm(const float* __restrict__ x,
                                             double* __restrict__ nrm) {
  int row = blockIdx.x * 4 + (threadIdx.x >> 6);
  int lane = threadIdx.x & 63;
  const float4* xr = reinterpret_cast<const float4*>(x + (size_t)row * F_);
  float4 v1 = xr[lane];
  float4 v2 = xr[lane + 64];
  double s = (double)v1.x * v1.x + (double)v1.y * v1.y +
             (double)v1.z * v1.z + (double)v1.w * v1.w +
             (double)v2.x * v2.x + (double)v2.y * v2.y +
             (double)v2.z * v2.z + (double)v2.w * v2.w;
#pragma unroll
  for (int off = 32; off > 0; off >>= 1) s += __shfl_down(s, off, 64);
  if (lane == 0) nrm[row] = sqrt(s);
}

// ---- bf16-MFMA Gram (hi*hi + hi*lo + lo*hi), binarize + band-flag ----
// LDS tiles XOR-swizzled: 16B-group g of row r stored at g^(r&7) (write AND read).
__global__ __launch_bounds__(256) void kgram2(const ushort* __restrict__ xhi,
                                              const ushort* __restrict__ xlo,
                                              const double* __restrict__ nrm,
                                              uint32_t* __restrict__ bits,
                                              uint32_t* __restrict__ flagn,
                                              uint32_t* __restrict__ flags) {
  int b = blockIdx.y;
  int tt = (int)blockIdx.x, I = 0;
  while (tt >= TTILES - I) { tt -= TTILES - I; ++I; }
  int J = I + tt;
  bool offdiag = (I != J);
  int c0 = I * 64, d0 = J * 64;
  int tid = threadIdx.x;
  int l = tid & 63, w = tid >> 6;
  int wc = w >> 1, wf = w & 1;      // wave -> 32x32 (c,d) sub-tile
  int lg = l >> 4, li = l & 15;

  __shared__ ushort sm[4 * 64 * 64];   // Ahi | Alo | Bhi | Blo, each [64][64] swizzled
  __shared__ uint32_t lb[64][2];
  __shared__ uint32_t lbT[64][2];

  f32x4 acc[2][2];
#pragma unroll
  for (int m = 0; m < 2; ++m)
#pragma unroll
    for (int n = 0; n < 2; ++n) acc[m][n] = (f32x4){0.f, 0.f, 0.f, 0.f};

  const size_t xbase = (size_t)b * C_ * F_;

  for (int kc = 0; kc < F_ / 64; ++kc) {
    __syncthreads();
    // stage 4 tiles (64 rows x 64 bf16 each), reg-staged, swizzled ds-write
#pragma unroll
    for (int s = 0; s < 8; ++s) {
      int is = w + s * 4;                 // 0..31
      int tile = is >> 3, sub = is & 7;
      const ushort* src = (tile & 1) ? xlo : xhi;
      int rbase = (tile < 2) ? c0 : d0;
      int row = sub * 8 + (l >> 3);
      int g = l & 7;
      uint4 v = *reinterpret_cast<const uint4*>(
          src + xbase + (size_t)(rbase + row) * F_ + kc * 64 + g * 8);
      int ldsoff = tile * 4096 + row * 64 + ((g ^ (row & 7)) * 8);
      *reinterpret_cast<uint4*>(&sm[ldsoff]) = v;
    }
    __syncthreads();
#pragma unroll
    for (int kk = 0; kk < 2; ++kk) {
      bf16x8 ah[2], al[2], bh[2], bl[2];
#pragma unroll
      for (int m = 0; m < 2; ++m) {
        int row = wc * 32 + m * 16 + li;
        int off = row * 64 + (((kk * 4 + lg) ^ (row & 7)) * 8);
        ah[m] = *reinterpret_cast<const bf16x8*>(&sm[off]);
        al[m] = *reinterpret_cast<const bf16x8*>(&sm[4096 + off]);
      }
#pragma unroll
      for (int n = 0; n < 2; ++n) {
        int row = wf * 32 + n * 16 + li;
        int off = row * 64 + (((kk * 4 + lg) ^ (row & 7)) * 8);
        bh[n] = *reinterpret_cast<const bf16x8*>(&sm[8192 + off]);
        bl[n] = *reinterpret_cast<const bf16x8*>(&sm[12288 + off]);
      }
#pragma unroll
      for (int m = 0; m < 2; ++m)
#pragma unroll
        for (int n = 0; n < 2; ++n) {
          acc[m][n] = __builtin_amdgcn_mfma_f32_16x16x32_bf16(ah[m], bh[n], acc[m][n], 0, 0, 0);
          acc[m][n] = __builtin_amdgcn_mfma_f32_16x16x32_bf16(ah[m], bl[n], acc[m][n], 0, 0, 0);
          acc[m][n] = __builtin_amdgcn_mfma_f32_16x16x32_bf16(al[m], bh[n], acc[m][n], 0, 0, 0);
        }
    }
  }

  // epilogue: binarize vs fp64 thresholds, ballot-assemble bit tile, flag band pairs
  double ncv[2][4], ndv[2];
#pragma unroll
  for (int m = 0; m < 2; ++m)
#pragma unroll
    for (int q = 0; q < 4; ++q)
      ncv[m][q] = nrm[b * C_ + c0 + wc * 32 + m * 16 + lg * 4 + q];
#pragma unroll
  for (int n = 0; n < 2; ++n)
    ndv[n] = nrm[b * C_ + d0 + wf * 32 + n * 16 + li];

#pragma unroll
  for (int m = 0; m < 2; ++m) {
#pragma unroll
    for (int q = 0; q < 4; ++q) {
      uint32_t wv = 0;
#pragma unroll
      for (int n = 0; n < 2; ++n) {
        float num = acc[m][n][q];
        float tq = (float)(0.005 * ncv[m][q] * ndv[n]);
        bool bit = num > tq;
        if (fabsf(num - tq) < BAND) {
          uint32_t idx = atomicAdd(flagn, 1u);
          if (idx < FLAGCAP) {
            int cc = c0 + wc * 32 + m * 16 + lg * 4 + q;
            int dd = d0 + wf * 32 + n * 16 + li;
            flags[idx] = ((uint32_t)b << 22) | ((uint32_t)cc << 11) | (uint32_t)dd;
          }
        }
        unsigned long long bal = __ballot(bit);
        uint32_t b16 = (uint32_t)((bal >> (lg * 16)) & 0xFFFFull);
        wv |= b16 << (n * 16);
      }
      if (li == 0) lb[wc * 32 + m * 16 + lg * 4 + q][wf] = wv;   // unique writer
    }
  }
  __syncthreads();
  if (offdiag && tid < 64) {          // transpose bit tile
    uint32_t w0 = 0, w1 = 0;
    int word = tid >> 5, sh = tid & 31;
    for (int c = 0; c < 32; ++c)  w0 |= ((lb[c][word] >> sh) & 1u) << c;
    for (int c = 32; c < 64; ++c) w1 |= ((lb[c][word] >> sh) & 1u) << (c - 32);
    lbT[tid][0] = w0; lbT[tid][1] = w1;
  }
  __syncthreads();
  if (tid < 64) {
    size_t base = ((size_t)b * C_ + c0 + tid) * 64 + (size_t)J * 2;
    bits[base] = lb[tid][0]; bits[base + 1] = lb[tid][1];
  } else if (offdiag && tid < 128) {
    int r = tid - 64;
    size_t base = ((size_t)b * C_ + d0 + r) * 64 + (size_t)I * 2;
    bits[base] = lbT[r][0]; bits[base + 1] = lbT[r][1];
  }
}

// ---- exact fp64 re-decision for band pairs; one wave per pair ----
__global__ __launch_bounds__(256) void krepair(const float* __restrict__ x,
                                               const double* __restrict__ nrm,
                                               const uint32_t* __restrict__ flagn,
                                               const uint32_t* __restrict__ flags,
                                               uint32_t* __restrict__ bits) {
  int l = threadIdx.x & 63;
  uint32_t wave = (blockIdx.x * 256 + threadIdx.x) >> 6;
  uint32_t nwaves = (gridDim.x * 256) >> 6;
  uint32_t nf = *flagn; if (nf > FLAGCAP) nf = FLAGCAP;
  for (uint32_t p = wave; p < nf; p += nwaves) {
    uint32_t e = flags[p];
    int b = e >> 22, c = (e >> 11) & 2047, d = e & 2047;
    const float* xc = x + ((size_t)b * C_ + c) * F_;
    const float* xd = x + ((size_t)b * C_ + d) * F_;
    double s = 0.0;
#pragma unroll
    for (int j = 0; j < 8; ++j) {
      int k = l * 8 + j;
      s += (double)xc[k] * (double)xd[k];
    }
#pragma unroll
    for (int off = 32; off > 0; off >>= 1) s += __shfl_down(s, off, 64);
    if (l == 0) {
      bool bit = s > 0.005 * nrm[b * C_ + c] * nrm[b * C_ + d];
      uint32_t* wcd = bits + (((size_t)b * C_ + c) << 6) + (d >> 5);
      uint32_t* wdc = bits + (((size_t)b * C_ + d) << 6) + (c >> 5);
      uint32_t mcd = 1u << (d & 31), mdc = 1u << (c & 31);
      if (bit) { atomicOr(wcd, mcd);  atomicOr(wdc, mdc); }
      else     { atomicAnd(wcd, ~mcd); atomicAnd(wdc, ~mdc); }
    }
  }
}

// ---- degree by popcount -> sinv ----
__global__ __launch_bounds__(256) void kdeg(const uint32_t* __restrict__ bits,
                                            float* __restrict__ sinv) {
  int row = blockIdx.x * 256 + threadIdx.x;
  const uint4* p = reinterpret_cast<const uint4*>(bits + ((size_t)row << 6));
  uint32_t s = 0;
#pragma unroll
  for (int i = 0; i < 16; ++i) {
    uint4 v = p[i];
    s += __popc(v.x) + __popc(v.y) + __popc(v.z) + __popc(v.w);
  }
  sinv[row] = 1.0f / sqrtf((float)s);
}

// ---- dense GEMM (fp32): g = A @ W ----
__global__ __launch_bounds__(256) void kgemm_plain(const float* __restrict__ A,
                                                   const float* __restrict__ W,
                                                   float* __restrict__ out) {
  int m0 = blockIdx.x * 64, n0 = blockIdx.y * 64;
  int tid = threadIdx.x, tx = tid & 15, ty = tid >> 4;
  __shared__ __align__(16) float As[16][68];
  __shared__ __align__(16) float Bs[16][68];
  float acc[4][4];
#pragma unroll
  for (int i = 0; i < 4; ++i)
#pragma unroll
    for (int j = 0; j < 4; ++j) acc[i][j] = 0.f;

  for (int kc = 0; kc < F_ / 16; ++kc) {
    int k0 = kc * 16;
#pragma unroll
    for (int p = 0; p < 4; ++p) {
      int r = (tid >> 4) + p * 16;
      int k = tid & 15;
      As[k][r] = A[(size_t)(m0 + r) * F_ + k0 + k];
    }
    {
      int k = tid >> 4;
      int col = (tid & 15) * 4;
      float4 v = *reinterpret_cast<const float4*>(&W[(size_t)(k0 + k) * F_ + n0 + col]);
      *reinterpret_cast<float4*>(&Bs[k][col]) = v;
    }
    __syncthreads();
#pragma unroll
    for (int kk = 0; kk < 16; ++kk) {
      float4 a = *reinterpret_cast<const float4*>(&As[kk][ty * 4]);
      float4 bv = *reinterpret_cast<const float4*>(&Bs[kk][tx * 4]);
      acc[0][0] = fmaf(a.x, bv.x, acc[0][0]); acc[0][1] = fmaf(a.x, bv.y, acc[0][1]);
      acc[0][2] = fmaf(a.x, bv.z, acc[0][2]); acc[0][3] = fmaf(a.x, bv.w, acc[0][3]);
      acc[1][0] = fmaf(a.y, bv.x, acc[1][0]); acc[1][1] = fmaf(a.y, bv.y, acc[1][1]);
      acc[1][2] = fmaf(a.y, bv.z, acc[1][2]); acc[1][3] = fmaf(a.y, bv.w, acc[1][3]);
      acc[2][0] = fmaf(a.z, bv.x, acc[2][0]); acc[2][1] = fmaf(a.z, bv.y, acc[2][1]);
      acc[2][2] = fmaf(a.z, bv.z, acc[2][2]); acc[2][3] = fmaf(a.z, bv.w, acc[2][3]);
      acc[3][0] = fmaf(a.w, bv.x, acc[3][0]); acc[3][1] = fmaf(a.w, bv.y, acc[3][1]);
      acc[3][2] = fmaf(a.w, bv.z, acc[3][2]); acc[3][3] = fmaf(a.w, bv.w, acc[3][3]);
    }
    __syncthreads();
  }
#pragma unroll
  for (int i = 0; i < 4; ++i) {
    float4 o = make_float4(acc[i][0], acc[i][1], acc[i][2], acc[i][3]);
    *reinterpret_cast<float4*>(&out[(size_t)(m0 + ty * 4 + i) * F_ + n0 + tx * 4]) = o;
  }
}

// ---- MFMA propagation: out = relu(s_c * sum_d mask[c,d]*(s_d*g[d,f]) + bias) ----
__global__ __launch_bounds__(256) void kprop_fused(const float* __restrict__ g,
                                                   const float* __restrict__ sinv,
                                                   const uint32_t* __restrict__ bits,
                                                   const float* __restrict__ bias,
                                                   float* __restrict__ out) {
  int b = blockIdx.z;
  int c0 = blockIdx.x * 64, f0 = blockIdx.y * 64;
  int tid = threadIdx.x;
  int l = tid & 63, w = tid >> 6;
  int wc = w >> 1, wf = w & 1;
  int lg = l >> 4, li = l & 15;

  __shared__ ushort vhi[64][72];
  __shared__ ushort vlo[64][72];
  __shared__ uint32_t blds[64][68];

  const uint32_t* bp = bits + (((size_t)b * C_ + c0) << 6);
#pragma unroll
  for (int t = 0; t < 4; ++t) {
    int gi = (t * 256 + tid) * 4;
    uint4 q = *reinterpret_cast<const uint4*>(bp + gi);
    int row = gi >> 6, col = gi & 63;
    *reinterpret_cast<uint4*>(&blds[row][col]) = q;
  }

  f32x4 acc[2][2];
#pragma unroll
  for (int m = 0; m < 2; ++m)
#pragma unroll
    for (int n = 0; n < 2; ++n) acc[m][n] = (f32x4){0.f, 0.f, 0.f, 0.f};

  const float* gb = g + (size_t)b * C_ * F_;
  const float* sv = sinv + b * C_;
  int r = tid >> 4;
  int fq = tid & 15;

  for (int d0 = 0; d0 < C_; d0 += 64) {
    __syncthreads();
#pragma unroll
    for (int p = 0; p < 2; ++p) {
      int dl = p * 32 + 2 * r;
      float s0 = sv[d0 + dl], s1 = sv[d0 + dl + 1];
      const float* g0 = &gb[(size_t)(d0 + dl) * F_ + f0];
      const float* g1 = g0 + F_;
#pragma unroll
      for (int j = 0; j < 4; ++j) {
        int fp = fq + 16 * j;
        float v0 = s0 * g0[fp];
        float v1 = s1 * g1[fp];
        __hip_bfloat16 h0 = __float2bfloat16(v0);
        __hip_bfloat16 h1 = __float2bfloat16(v1);
        __hip_bfloat16 e0 = __float2bfloat16(v0 - __bfloat162float(h0));
        __hip_bfloat16 e1 = __float2bfloat16(v1 - __bfloat162float(h1));
        uint32_t ph = (uint32_t)__builtin_bit_cast(unsigned short, h0) |
                      ((uint32_t)__builtin_bit_cast(unsigned short, h1) << 16);
        uint32_t pl = (uint32_t)__builtin_bit_cast(unsigned short, e0) |
                      ((uint32_t)__builtin_bit_cast(unsigned short, e1) << 16);
        *reinterpret_cast<uint32_t*>(&vhi[fp][dl]) = ph;
        *reinterpret_cast<uint32_t*>(&vlo[fp][dl]) = pl;
      }
    }
    __syncthreads();

    int wbase = d0 >> 5;
#pragma unroll
    for (int kk = 0; kk < 2; ++kk) {
      uint32_t wd0 = blds[wc * 32 + li][wbase + kk];
      uint32_t wd1 = blds[wc * 32 + 16 + li][wbase + kk];
      uint32_t by0 = (wd0 >> (lg * 8)) & 0xFFu;
      uint32_t by1 = (wd1 >> (lg * 8)) & 0xFFu;
      bf16x8 a0, a1;
#pragma unroll
      for (int j = 0; j < 8; ++j) {
        a0[j] = (short)(((by0 >> j) & 1u) ? 0x3F80 : 0);
        a1[j] = (short)(((by1 >> j) & 1u) ? 0x3F80 : 0);
      }
      int dk = kk * 32 + lg * 8;
      bf16x8 bh0 = *reinterpret_cast<const bf16x8*>(&vhi[wf * 32 + li][dk]);
      bf16x8 bl0 = *reinterpret_cast<const bf16x8*>(&vlo[wf * 32 + li][dk]);
      bf16x8 bh1 = *reinterpret_cast<const bf16x8*>(&vhi[wf * 32 + 16 + li][dk]);
      bf16x8 bl1 = *reinterpret_cast<const bf16x8*>(&vlo[wf * 32 + 16 + li][dk]);
      acc[0][0] = __builtin_amdgcn_mfma_f32_16x16x32_bf16(a0, bh0, acc[0][0], 0, 0, 0);
      acc[0][0] = __builtin_amdgcn_mfma_f32_16x16x32_bf16(a0, bl0, acc[0][0], 0, 0, 0);
      acc[0][1] = __builtin_amdgcn_mfma_f32_16x16x32_bf16(a0, bh1, acc[0][1], 0, 0, 0);
      acc[0][1] = __builtin_amdgcn_mfma_f32_16x16x32_bf16(a0, bl1, acc[0][1], 0, 0, 0);
      acc[1][0] = __builtin_amdgcn_mfma_f32_16x16x32_bf16(a1, bh0, acc[1][0], 0, 0, 0);
      acc[1][0] = __builtin_amdgcn_mfma_f32_16x16x32_bf16(a1, bl0, acc[1][0], 0, 0, 0);
      acc[1][1] = __builtin_amdgcn_mfma_f32_16x16x32_bf16(a1, bh1, acc[1][1], 0, 0, 0);
      acc[1][1] = __builtin_amdgcn_mfma_f32_16x16x32_bf16(a1, bl1, acc[1][1], 0, 0, 0);
    }
  }

  float bb = bias[0];
#pragma unroll
  for (int m = 0; m < 2; ++m) {
    int rowb = c0 + wc * 32 + m * 16 + lg * 4;
    f32x4 sc = *reinterpret_cast<const f32x4*>(&sv[rowb]);
#pragma unroll
    for (int n = 0; n < 2; ++n) {
      int col = f0 + wf * 32 + n * 16 + li;
#pragma unroll
      for (int q = 0; q < 4; ++q) {
        float o = sc[q] * acc[m][n][q] + bb;
        out[(size_t)(b * C_ + rowb + q) * F_ + col] = fmaxf(o, 0.f);
      }
    }
  }
}

extern "C" void kernel_launch(void* const* d_in, const int* in_sizes, int n_in,
                              void* d_out, int out_size, void* d_ws, size_t ws_size,
                              hipStream_t stream) {
  (void)in_sizes; (void)n_in; (void)out_size; (void)ws_size;
  const float* x  = (const float*)d_in[0];
  const float* W1 = (const float*)d_in[1];
  const float* b1 = (const float*)d_in[2];
  const float* W2 = (const float*)d_in[3];
  const float* b2 = (const float*)d_in[4];
  float* out = (float*)d_out;

  char* ws = (char*)d_ws;
  double*   nrm   = (double*)(ws);
  uint32_t* bits  = (uint32_t*)(ws + 131072);
  float*    sinv  = (float*)(ws + 4325376);
  uint32_t* flagn = (uint32_t*)(ws + 4390912);
  uint32_t* flags = (uint32_t*)(ws + 4391168);
  ushort*   xhi   = (ushort*)(ws + 8585472);
  ushort*   xlo   = (ushort*)(ws + 25362688);
  float*    g     = (float*)(ws + 8585472);   // overlays xhi/xlo (dead after kgram2)

  kzero1<<<dim3(1), 64, 0, stream>>>(flagn);
  ksplit<<<dim3(B_ * C_ * F_ / 2048), 256, 0, stream>>>(x, xhi, xlo);
  knorm<<<dim3(B_ * C_ / 4), 256, 0, stream>>>(x, nrm);
  kgram2<<<dim3(NPAIRS, B_), 256, 0, stream>>>(xhi, xlo, nrm, bits, flagn, flags);
  krepair<<<dim3(256), 256, 0, stream>>>(x, nrm, flagn, flags, bits);
  kdeg<<<dim3(B_ * C_ / 256), 256, 0, stream>>>(bits, sinv);

  // layer 1: g = x @ W1 ; h1 = relu(L @ g + b1)  -> d_out
  kgemm_plain<<<dim3(B_ * C_ / 64, F_ / 64), 256, 0, stream>>>(x, W1, g);
  kprop_fused<<<dim3(TTILES, F_ / 64, B_), 256, 0, stream>>>(g, sinv, bits, b1, out);
  // layer 2: g = h1 @ W2 ; out = relu(L @ g + b2) -> d_out
  kgemm_plain<<<dim3(B_ * C_ / 64, F_ / 64), 256, 0, stream>>>(out, W2, g);
  kprop_fused<<<dim3(TTILES, F_ / 64, B_), 256, 0, stream>>>(g, sinv, bits, b2, out);
}

// Round 6
// 514.797 us; speedup vs baseline: 3.5597x; 1.4726x over previous
//
#include <hip/hip_runtime.h>
#include <hip/hip_bf16.h>
#include <cstdint>
#include <cstddef>

#define B_ 8
#define C_ 2048
#define F_ 512
#define TTILES 32            // C_/64
#define NPAIRS 528           // TTILES*(TTILES+1)/2
#define BAND 0.015f
#define FLAGCAP (1u << 18)

typedef short bf16x8 __attribute__((ext_vector_type(8)));
typedef float f32x4 __attribute__((ext_vector_type(4)));

// ---------------------------------------------------------------------------
// ws layout (bytes):
//   nrm   double[16384]      @ 0          131072
//   bits  uint32[16384*64]   @ 131072     4194304
//   sinv  float[16384]       @ 4325376    65536
//   flagn uint32             @ 4390912    256
//   flags uint32[256K]       @ 4391168    1048576
//   wt    ushort[4*256K]     @ 5439744    2097152   (W1hi,W1lo,W2hi,W2lo; [n][k])
//   xhi   ushort[8M]         @ 7536896    16777216  (later reused as h1hi)
//   xlo   ushort[8M]         @ 24314112   16777216  (later reused as h1lo)
//   gthi  ushort[8M]         @ 41091328   16777216  (v^T hi, [b][f][d])
//   gtlo  ushort[8M]         @ 57868544   16777216
// total 74.6 MB
// ---------------------------------------------------------------------------

__device__ __forceinline__ ushort bf16hi(float v) {
  return __builtin_bit_cast(unsigned short, __float2bfloat16(v));
}

__device__ __forceinline__ int swz2048(int flat) {   // bijective XCD swizzle, 2048 % 8 == 0
  return (flat & 7) * 256 + (flat >> 3);
}

__global__ __launch_bounds__(64) void kzero1(uint32_t* __restrict__ flagn) {
  if (threadIdx.x == 0) *flagn = 0u;
}

// ---- split x into bf16 hi + lo ----
__global__ __launch_bounds__(256) void ksplit(const float* __restrict__ x,
                                              ushort* __restrict__ xhi,
                                              ushort* __restrict__ xlo) {
  size_t i = ((size_t)blockIdx.x * 256 + threadIdx.x) * 8;
  float4 v0 = *reinterpret_cast<const float4*>(x + i);
  float4 v1 = *reinterpret_cast<const float4*>(x + i + 4);
  float vv[8] = {v0.x, v0.y, v0.z, v0.w, v1.x, v1.y, v1.z, v1.w};
  ushort h[8], lo[8];
#pragma unroll
  for (int j = 0; j < 8; ++j) {
    ushort hh = bf16hi(vv[j]);
    float hf = __bfloat162float(__builtin_bit_cast(__hip_bfloat16, hh));
    h[j] = hh; lo[j] = bf16hi(vv[j] - hf);
  }
  *reinterpret_cast<uint4*>(xhi + i) = *reinterpret_cast<uint4*>(h);
  *reinterpret_cast<uint4*>(xlo + i) = *reinterpret_cast<uint4*>(lo);
}

// ---- transpose + split W (both layers): wt[n][k] bf16 hi/lo ----
__global__ __launch_bounds__(256) void kwsplit(const float* __restrict__ W1,
                                               const float* __restrict__ W2,
                                               ushort* __restrict__ wtbuf) {
  const float* W = blockIdx.z ? W2 : W1;
  ushort* whi = wtbuf + (size_t)blockIdx.z * 524288;
  ushort* wlo = whi + 262144;
  int k0 = blockIdx.x * 64, n0 = blockIdx.y * 64, tid = threadIdx.x;
  __shared__ float t[64][65];
#pragma unroll
  for (int it = 0; it < 4; ++it) {
    int slot = tid + it * 256;
    int row = slot >> 4, c4 = slot & 15;
    float4 v = *reinterpret_cast<const float4*>(&W[(size_t)(k0 + row) * 512 + n0 + c4 * 4]);
    t[row][c4 * 4 + 0] = v.x; t[row][c4 * 4 + 1] = v.y;
    t[row][c4 * 4 + 2] = v.z; t[row][c4 * 4 + 3] = v.w;
  }
  __syncthreads();
#pragma unroll
  for (int it = 0; it < 2; ++it) {
    int slot = tid + it * 256;
    int n = slot >> 3, g = slot & 7;
    ushort h8[8], l8[8];
#pragma unroll
    for (int j = 0; j < 8; ++j) {
      float v = t[g * 8 + j][n];
      ushort hh = bf16hi(v);
      float hf = __bfloat162float(__builtin_bit_cast(__hip_bfloat16, hh));
      h8[j] = hh; l8[j] = bf16hi(v - hf);
    }
    size_t ga = (size_t)(n0 + n) * 512 + k0 + g * 8;
    *reinterpret_cast<uint4*>(&whi[ga]) = *reinterpret_cast<uint4*>(h8);
    *reinterpret_cast<uint4*>(&wlo[ga]) = *reinterpret_cast<uint4*>(l8);
  }
}

__global__ __launch_bounds__(256) void knorm(const float* __restrict__ x,
                                             double* __restrict__ nrm) {
  int row = blockIdx.x * 4 + (threadIdx.x >> 6);
  int lane = threadIdx.x & 63;
  const float4* xr = reinterpret_cast<const float4*>(x + (size_t)row * F_);
  float4 v1 = xr[lane];
  float4 v2 = xr[lane + 64];
  double s = (double)v1.x * v1.x + (double)v1.y * v1.y +
             (double)v1.z * v1.z + (double)v1.w * v1.w +
             (double)v2.x * v2.x + (double)v2.y * v2.y +
             (double)v2.z * v2.z + (double)v2.w * v2.w;
#pragma unroll
  for (int off = 32; off > 0; off >>= 1) s += __shfl_down(s, off, 64);
  if (lane == 0) nrm[row] = sqrt(s);
}

// ---- bf16-MFMA Gram (hi*hi + hi*lo + lo*hi), binarize + band-flag ----
__global__ __launch_bounds__(256) void kgram2(const ushort* __restrict__ xhi,
                                              const ushort* __restrict__ xlo,
                                              const double* __restrict__ nrm,
                                              uint32_t* __restrict__ bits,
                                              uint32_t* __restrict__ flagn,
                                              uint32_t* __restrict__ flags) {
  int b = blockIdx.y;
  int tt = (int)blockIdx.x, I = 0;
  while (tt >= TTILES - I) { tt -= TTILES - I; ++I; }
  int J = I + tt;
  bool offdiag = (I != J);
  int c0 = I * 64, d0 = J * 64;
  int tid = threadIdx.x;
  int l = tid & 63, w = tid >> 6;
  int wc = w >> 1, wf = w & 1;
  int lg = l >> 4, li = l & 15;

  __shared__ ushort sm[4 * 64 * 64];
  __shared__ uint32_t lb[64][2];
  __shared__ uint32_t lbT[64][2];

  f32x4 acc[2][2];
#pragma unroll
  for (int m = 0; m < 2; ++m)
#pragma unroll
    for (int n = 0; n < 2; ++n) acc[m][n] = (f32x4){0.f, 0.f, 0.f, 0.f};

  const size_t xbase = (size_t)b * C_ * F_;

  for (int kc = 0; kc < F_ / 64; ++kc) {
    __syncthreads();
#pragma unroll
    for (int s = 0; s < 8; ++s) {
      int is = w + s * 4;
      int tile = is >> 3, sub = is & 7;
      const ushort* src = (tile & 1) ? xlo : xhi;
      int rbase = (tile < 2) ? c0 : d0;
      int row = sub * 8 + (l >> 3);
      int g = l & 7;
      uint4 v = *reinterpret_cast<const uint4*>(
          src + xbase + (size_t)(rbase + row) * F_ + kc * 64 + g * 8);
      int ldsoff = tile * 4096 + row * 64 + ((g ^ (row & 7)) * 8);
      *reinterpret_cast<uint4*>(&sm[ldsoff]) = v;
    }
    __syncthreads();
#pragma unroll
    for (int kk = 0; kk < 2; ++kk) {
      bf16x8 ah[2], al[2], bh[2], bl[2];
#pragma unroll
      for (int m = 0; m < 2; ++m) {
        int row = wc * 32 + m * 16 + li;
        int off = row * 64 + (((kk * 4 + lg) ^ (row & 7)) * 8);
        ah[m] = *reinterpret_cast<const bf16x8*>(&sm[off]);
        al[m] = *reinterpret_cast<const bf16x8*>(&sm[4096 + off]);
      }
#pragma unroll
      for (int n = 0; n < 2; ++n) {
        int row = wf * 32 + n * 16 + li;
        int off = row * 64 + (((kk * 4 + lg) ^ (row & 7)) * 8);
        bh[n] = *reinterpret_cast<const bf16x8*>(&sm[8192 + off]);
        bl[n] = *reinterpret_cast<const bf16x8*>(&sm[12288 + off]);
      }
#pragma unroll
      for (int m = 0; m < 2; ++m)
#pragma unroll
        for (int n = 0; n < 2; ++n) {
          acc[m][n] = __builtin_amdgcn_mfma_f32_16x16x32_bf16(ah[m], bh[n], acc[m][n], 0, 0, 0);
          acc[m][n] = __builtin_amdgcn_mfma_f32_16x16x32_bf16(ah[m], bl[n], acc[m][n], 0, 0, 0);
          acc[m][n] = __builtin_amdgcn_mfma_f32_16x16x32_bf16(al[m], bh[n], acc[m][n], 0, 0, 0);
        }
    }
  }

  double ncv[2][4], ndv[2];
#pragma unroll
  for (int m = 0; m < 2; ++m)
#pragma unroll
    for (int q = 0; q < 4; ++q)
      ncv[m][q] = nrm[b * C_ + c0 + wc * 32 + m * 16 + lg * 4 + q];
#pragma unroll
  for (int n = 0; n < 2; ++n)
    ndv[n] = nrm[b * C_ + d0 + wf * 32 + n * 16 + li];

#pragma unroll
  for (int m = 0; m < 2; ++m) {
#pragma unroll
    for (int q = 0; q < 4; ++q) {
      uint32_t wv = 0;
#pragma unroll
      for (int n = 0; n < 2; ++n) {
        float num = acc[m][n][q];
        float tq = (float)(0.005 * ncv[m][q] * ndv[n]);
        bool bit = num > tq;
        if (fabsf(num - tq) < BAND) {
          uint32_t idx = atomicAdd(flagn, 1u);
          if (idx < FLAGCAP) {
            int cc = c0 + wc * 32 + m * 16 + lg * 4 + q;
            int dd = d0 + wf * 32 + n * 16 + li;
            flags[idx] = ((uint32_t)b << 22) | ((uint32_t)cc << 11) | (uint32_t)dd;
          }
        }
        unsigned long long bal = __ballot(bit);
        uint32_t b16 = (uint32_t)((bal >> (lg * 16)) & 0xFFFFull);
        wv |= b16 << (n * 16);
      }
      if (li == 0) lb[wc * 32 + m * 16 + lg * 4 + q][wf] = wv;
    }
  }
  __syncthreads();
  if (offdiag && tid < 64) {
    uint32_t w0 = 0, w1 = 0;
    int word = tid >> 5, sh = tid & 31;
    for (int c = 0; c < 32; ++c)  w0 |= ((lb[c][word] >> sh) & 1u) << c;
    for (int c = 32; c < 64; ++c) w1 |= ((lb[c][word] >> sh) & 1u) << (c - 32);
    lbT[tid][0] = w0; lbT[tid][1] = w1;
  }
  __syncthreads();
  if (tid < 64) {
    size_t base = ((size_t)b * C_ + c0 + tid) * 64 + (size_t)J * 2;
    bits[base] = lb[tid][0]; bits[base + 1] = lb[tid][1];
  } else if (offdiag && tid < 128) {
    int r = tid - 64;
    size_t base = ((size_t)b * C_ + d0 + r) * 64 + (size_t)I * 2;
    bits[base] = lbT[r][0]; bits[base + 1] = lbT[r][1];
  }
}

// ---- exact fp64 re-decision for band pairs ----
__global__ __launch_bounds__(256) void krepair(const float* __restrict__ x,
                                               const double* __restrict__ nrm,
                                               const uint32_t* __restrict__ flagn,
                                               const uint32_t* __restrict__ flags,
                                               uint32_t* __restrict__ bits) {
  int l = threadIdx.x & 63;
  uint32_t wave = (blockIdx.x * 256 + threadIdx.x) >> 6;
  uint32_t nwaves = (gridDim.x * 256) >> 6;
  uint32_t nf = *flagn; if (nf > FLAGCAP) nf = FLAGCAP;
  for (uint32_t p = wave; p < nf; p += nwaves) {
    uint32_t e = flags[p];
    int b = e >> 22, c = (e >> 11) & 2047, d = e & 2047;
    const float* xc = x + ((size_t)b * C_ + c) * F_;
    const float* xd = x + ((size_t)b * C_ + d) * F_;
    double s = 0.0;
#pragma unroll
    for (int j = 0; j < 8; ++j) {
      int k = l * 8 + j;
      s += (double)xc[k] * (double)xd[k];
    }
#pragma unroll
    for (int off = 32; off > 0; off >>= 1) s += __shfl_down(s, off, 64);
    if (l == 0) {
      bool bit = s > 0.005 * nrm[b * C_ + c] * nrm[b * C_ + d];
      uint32_t* wcd = bits + (((size_t)b * C_ + c) << 6) + (d >> 5);
      uint32_t* wdc = bits + (((size_t)b * C_ + d) << 6) + (c >> 5);
      uint32_t mcd = 1u << (d & 31), mdc = 1u << (c & 31);
      if (bit) { atomicOr(wcd, mcd);  atomicOr(wdc, mdc); }
      else     { atomicAnd(wcd, ~mcd); atomicAnd(wdc, ~mdc); }
    }
  }
}

__global__ __launch_bounds__(256) void kdeg(const uint32_t* __restrict__ bits,
                                            float* __restrict__ sinv) {
  int row = blockIdx.x * 256 + threadIdx.x;
  const uint4* p = reinterpret_cast<const uint4*>(bits + ((size_t)row << 6));
  uint32_t s = 0;
#pragma unroll
  for (int i = 0; i < 16; ++i) {
    uint4 v = p[i];
    s += __popc(v.x) + __popc(v.y) + __popc(v.z) + __popc(v.w);
  }
  sinv[row] = 1.0f / sqrtf((float)s);
}

// ---- split-bf16 MFMA GEMM: v^T = (sinv .* (A @ W))^T, written as hi/lo bf16 ----
// A: [M=B*C][K=512] bf16 hi/lo; Wt: [n][k] bf16 hi/lo; out gT: [b][f][d] hi/lo
__global__ __launch_bounds__(256) void kgemm_mfma(const ushort* __restrict__ ahi,
                                                  const ushort* __restrict__ alo,
                                                  const ushort* __restrict__ wthi,
                                                  const ushort* __restrict__ wtlo,
                                                  const float* __restrict__ sinv,
                                                  ushort* __restrict__ gthi,
                                                  ushort* __restrict__ gtlo) {
  int flat = (int)blockIdx.y * 256 + (int)blockIdx.x;
  int nid = swz2048(flat);
  int m0 = (nid & 255) * 64, n0 = (nid >> 8) * 64;
  int tid = threadIdx.x;
  int l = tid & 63, w = tid >> 6;
  int wc = w >> 1, wf = w & 1;
  int lg = l >> 4, li = l & 15;

  __shared__ ushort smA[2 * 4096];   // Ahi | Alo, swizzled [64][64]
  __shared__ ushort smW[2 * 4096];   // Whi | Wlo (Wt rows = n)

  f32x4 acc[2][2];
#pragma unroll
  for (int m = 0; m < 2; ++m)
#pragma unroll
    for (int n = 0; n < 2; ++n) acc[m][n] = (f32x4){0.f, 0.f, 0.f, 0.f};

  for (int kc = 0; kc < 8; ++kc) {
    int k0 = kc * 64;
    __syncthreads();
#pragma unroll
    for (int it = 0; it < 2; ++it) {
      int slot = tid + it * 256;
      int row = slot >> 3, grp = slot & 7;
      int loff = row * 64 + ((grp ^ (row & 7)) * 8);
      size_t ga = (size_t)(m0 + row) * 512 + k0 + grp * 8;
      *reinterpret_cast<uint4*>(&smA[loff])        = *reinterpret_cast<const uint4*>(ahi + ga);
      *reinterpret_cast<uint4*>(&smA[4096 + loff]) = *reinterpret_cast<const uint4*>(alo + ga);
      size_t gw = (size_t)(n0 + row) * 512 + k0 + grp * 8;
      *reinterpret_cast<uint4*>(&smW[loff])        = *reinterpret_cast<const uint4*>(wthi + gw);
      *reinterpret_cast<uint4*>(&smW[4096 + loff]) = *reinterpret_cast<const uint4*>(wtlo + gw);
    }
    __syncthreads();
#pragma unroll
    for (int kk = 0; kk < 2; ++kk) {
      bf16x8 ah[2], al[2], wh[2], wl[2];
#pragma unroll
      for (int m = 0; m < 2; ++m) {
        int row = wc * 32 + m * 16 + li;
        int off = row * 64 + (((kk * 4 + lg) ^ (row & 7)) * 8);
        ah[m] = *reinterpret_cast<const bf16x8*>(&smA[off]);
        al[m] = *reinterpret_cast<const bf16x8*>(&smA[4096 + off]);
      }
#pragma unroll
      for (int n = 0; n < 2; ++n) {
        int row = wf * 32 + n * 16 + li;
        int off = row * 64 + (((kk * 4 + lg) ^ (row & 7)) * 8);
        wh[n] = *reinterpret_cast<const bf16x8*>(&smW[off]);
        wl[n] = *reinterpret_cast<const bf16x8*>(&smW[4096 + off]);
      }
#pragma unroll
      for (int m = 0; m < 2; ++m)
#pragma unroll
        for (int n = 0; n < 2; ++n) {
          acc[m][n] = __builtin_amdgcn_mfma_f32_16x16x32_bf16(ah[m], wh[n], acc[m][n], 0, 0, 0);
          acc[m][n] = __builtin_amdgcn_mfma_f32_16x16x32_bf16(ah[m], wl[n], acc[m][n], 0, 0, 0);
          acc[m][n] = __builtin_amdgcn_mfma_f32_16x16x32_bf16(al[m], wh[n], acc[m][n], 0, 0, 0);
          acc[m][n] = __builtin_amdgcn_mfma_f32_16x16x32_bf16(al[m], wl[n], acc[m][n], 0, 0, 0);
        }
    }
  }

  // epilogue: v = sinv[m]*acc; split; write transposed gT[b][f][d] (d = channel)
  int b = m0 >> 11, cb = m0 & 2047;
#pragma unroll
  for (int m = 0; m < 2; ++m) {
    int rowl = wc * 32 + m * 16 + lg * 4;
    f32x4 sc = *reinterpret_cast<const f32x4*>(&sinv[m0 + rowl]);
#pragma unroll
    for (int n = 0; n < 2; ++n) {
      int f = n0 + wf * 32 + n * 16 + li;
      ushort h4[4], l4[4];
#pragma unroll
      for (int q = 0; q < 4; ++q) {
        float v = sc[q] * acc[m][n][q];
        ushort hh = bf16hi(v);
        float hf = __bfloat162float(__builtin_bit_cast(__hip_bfloat16, hh));
        h4[q] = hh; l4[q] = bf16hi(v - hf);
      }
      size_t ga = ((size_t)b * F_ + f) * C_ + cb + rowl;
      *reinterpret_cast<ushort4*>(&gthi[ga]) = *reinterpret_cast<ushort4*>(h4);
      *reinterpret_cast<ushort4*>(&gtlo[ga]) = *reinterpret_cast<ushort4*>(l4);
    }
  }
}

// ---- MFMA propagation: out = relu(s_c * sum_d mask[c,d]*v[d,f] + bias) ----
// v given pre-scaled/pre-split/transposed (gthi/gtlo). Dual output: bf16 hi/lo
// (h for next layer) or fp32 (final).
__global__ __launch_bounds__(256) void kprop_mfma(const ushort* __restrict__ gthi,
                                                  const ushort* __restrict__ gtlo,
                                                  const float* __restrict__ sinv,
                                                  const uint32_t* __restrict__ bits,
                                                  const float* __restrict__ bias,
                                                  ushort* __restrict__ ohi,
                                                  ushort* __restrict__ olo,
                                                  float* __restrict__ of32) {
  int nid = swz2048((int)blockIdx.x);
  int c0 = (nid & 31) * 64, f0 = ((nid >> 5) & 7) * 64, b = nid >> 8;
  int tid = threadIdx.x;
  int l = tid & 63, w = tid >> 6;
  int wc = w >> 1, wf = w & 1;
  int lg = l >> 4, li = l & 15;

  __shared__ ushort smv[2 * 4096];      // vThi | vTlo, swizzled [f][d]
  __shared__ uint32_t blds[64][68];

  const uint32_t* bp = bits + (((size_t)b * C_ + c0) << 6);
#pragma unroll
  for (int t = 0; t < 4; ++t) {
    int gi = (t * 256 + tid) * 4;
    uint4 q = *reinterpret_cast<const uint4*>(bp + gi);
    int row = gi >> 6, col = gi & 63;
    *reinterpret_cast<uint4*>(&blds[row][col]) = q;
  }

  f32x4 acc[2][2];
#pragma unroll
  for (int m = 0; m < 2; ++m)
#pragma unroll
    for (int n = 0; n < 2; ++n) acc[m][n] = (f32x4){0.f, 0.f, 0.f, 0.f};

  const float* sv = sinv + b * C_;

  for (int d0 = 0; d0 < C_; d0 += 64) {
    __syncthreads();
#pragma unroll
    for (int it = 0; it < 2; ++it) {
      int slot = tid + it * 256;
      int row = slot >> 3, grp = slot & 7;        // row = f, grp = d/8
      int loff = row * 64 + ((grp ^ (row & 7)) * 8);
      size_t ga = ((size_t)b * F_ + f0 + row) * C_ + d0 + grp * 8;
      *reinterpret_cast<uint4*>(&smv[loff])        = *reinterpret_cast<const uint4*>(gthi + ga);
      *reinterpret_cast<uint4*>(&smv[4096 + loff]) = *reinterpret_cast<const uint4*>(gtlo + ga);
    }
    __syncthreads();

    int wbase = d0 >> 5;
#pragma unroll
    for (int kk = 0; kk < 2; ++kk) {
      uint32_t wd0 = blds[wc * 32 + li][wbase + kk];
      uint32_t wd1 = blds[wc * 32 + 16 + li][wbase + kk];
      uint32_t by0 = (wd0 >> (lg * 8)) & 0xFFu;
      uint32_t by1 = (wd1 >> (lg * 8)) & 0xFFu;
      bf16x8 a0, a1;
#pragma unroll
      for (int j = 0; j < 8; ++j) {
        a0[j] = (short)(((by0 >> j) & 1u) ? 0x3F80 : 0);
        a1[j] = (short)(((by1 >> j) & 1u) ? 0x3F80 : 0);
      }
      bf16x8 bh0, bl0, bh1, bl1;
      {
        int row = wf * 32 + li;
        int off = row * 64 + (((kk * 4 + lg) ^ (row & 7)) * 8);
        bh0 = *reinterpret_cast<const bf16x8*>(&smv[off]);
        bl0 = *reinterpret_cast<const bf16x8*>(&smv[4096 + off]);
      }
      {
        int row = wf * 32 + 16 + li;
        int off = row * 64 + (((kk * 4 + lg) ^ (row & 7)) * 8);
        bh1 = *reinterpret_cast<const bf16x8*>(&smv[off]);
        bl1 = *reinterpret_cast<const bf16x8*>(&smv[4096 + off]);
      }
      acc[0][0] = __builtin_amdgcn_mfma_f32_16x16x32_bf16(a0, bh0, acc[0][0], 0, 0, 0);
      acc[0][0] = __builtin_amdgcn_mfma_f32_16x16x32_bf16(a0, bl0, acc[0][0], 0, 0, 0);
      acc[0][1] = __builtin_amdgcn_mfma_f32_16x16x32_bf16(a0, bh1, acc[0][1], 0, 0, 0);
      acc[0][1] = __builtin_amdgcn_mfma_f32_16x16x32_bf16(a0, bl1, acc[0][1], 0, 0, 0);
      acc[1][0] = __builtin_amdgcn_mfma_f32_16x16x32_bf16(a1, bh0, acc[1][0], 0, 0, 0);
      acc[1][0] = __builtin_amdgcn_mfma_f32_16x16x32_bf16(a1, bl0, acc[1][0], 0, 0, 0);
      acc[1][1] = __builtin_amdgcn_mfma_f32_16x16x32_bf16(a1, bh1, acc[1][1], 0, 0, 0);
      acc[1][1] = __builtin_amdgcn_mfma_f32_16x16x32_bf16(a1, bl1, acc[1][1], 0, 0, 0);
    }
  }

  float bb = bias[0];
#pragma unroll
  for (int m = 0; m < 2; ++m) {
    int rowb = c0 + wc * 32 + m * 16 + lg * 4;
    f32x4 sc = *reinterpret_cast<const f32x4*>(&sv[rowb]);
#pragma unroll
    for (int n = 0; n < 2; ++n) {
      int col = f0 + wf * 32 + n * 16 + li;
      if (of32) {
#pragma unroll
        for (int q = 0; q < 4; ++q) {
          float o = fmaxf(sc[q] * acc[m][n][q] + bb, 0.f);
          of32[((size_t)b * C_ + rowb + q) * F_ + col] = o;
        }
      } else {
#pragma unroll
        for (int q = 0; q < 4; ++q) {
          float o = fmaxf(sc[q] * acc[m][n][q] + bb, 0.f);
          ushort hh = bf16hi(o);
          float hf = __bfloat162float(__builtin_bit_cast(__hip_bfloat16, hh));
          size_t ga = ((size_t)b * C_ + rowb + q) * F_ + col;
          ohi[ga] = hh;
          olo[ga] = bf16hi(o - hf);
        }
      }
    }
  }
}

extern "C" void kernel_launch(void* const* d_in, const int* in_sizes, int n_in,
                              void* d_out, int out_size, void* d_ws, size_t ws_size,
                              hipStream_t stream) {
  (void)in_sizes; (void)n_in; (void)out_size; (void)ws_size;
  const float* x  = (const float*)d_in[0];
  const float* W1 = (const float*)d_in[1];
  const float* b1 = (const float*)d_in[2];
  const float* W2 = (const float*)d_in[3];
  const float* b2 = (const float*)d_in[4];
  float* out = (float*)d_out;

  char* ws = (char*)d_ws;
  double*   nrm   = (double*)(ws);
  uint32_t* bits  = (uint32_t*)(ws + 131072);
  float*    sinv  = (float*)(ws + 4325376);
  uint32_t* flagn = (uint32_t*)(ws + 4390912);
  uint32_t* flags = (uint32_t*)(ws + 4391168);
  ushort*   wt    = (ushort*)(ws + 5439744);
  ushort*   xhi   = (ushort*)(ws + 7536896);   // reused as h1hi after layer-1 kgemm
  ushort*   xlo   = (ushort*)(ws + 24314112);  // reused as h1lo
  ushort*   gthi  = (ushort*)(ws + 41091328);
  ushort*   gtlo  = (ushort*)(ws + 57868544);
  ushort*   wt1hi = wt, *wt1lo = wt + 262144, *wt2hi = wt + 524288, *wt2lo = wt + 786432;

  kzero1<<<dim3(1), 64, 0, stream>>>(flagn);
  ksplit<<<dim3(B_ * C_ * F_ / 2048), 256, 0, stream>>>(x, xhi, xlo);
  knorm<<<dim3(B_ * C_ / 4), 256, 0, stream>>>(x, nrm);
  kwsplit<<<dim3(8, 8, 2), 256, 0, stream>>>(W1, W2, wt);
  kgram2<<<dim3(NPAIRS, B_), 256, 0, stream>>>(xhi, xlo, nrm, bits, flagn, flags);
  krepair<<<dim3(256), 256, 0, stream>>>(x, nrm, flagn, flags, bits);
  kdeg<<<dim3(B_ * C_ / 256), 256, 0, stream>>>(bits, sinv);

  // layer 1: vT = (sinv.*(x@W1))^T ; h1(hi/lo) = relu(L-prop + b1) -> xhi/xlo
  kgemm_mfma<<<dim3(256, 8), 256, 0, stream>>>(xhi, xlo, wt1hi, wt1lo, sinv, gthi, gtlo);
  kprop_mfma<<<dim3(2048), 256, 0, stream>>>(gthi, gtlo, sinv, bits, b1, xhi, xlo, nullptr);
  // layer 2: vT = (sinv.*(h1@W2))^T ; out = relu(L-prop + b2) -> d_out (fp32)
  kgemm_mfma<<<dim3(256, 8), 256, 0, stream>>>(xhi, xlo, wt2hi, wt2lo, sinv, gthi, gtlo);
  kprop_mfma<<<dim3(2048), 256, 0, stream>>>(gthi, gtlo, sinv, bits, b2, nullptr, nullptr, out);
}